// Round 19
// baseline (731.681 us; speedup 1.0000x reference)
//
#include <hip/hip_runtime.h>

#define N_NODES 100000
#define N_EDGES 3200000
#define F_IN    1433
#define HID     16
#define N_CLS   7
#define NWINT   48                                   // K windows of 32 (K padded to 1536)
#define NWIN    12                                   // windows per wave (4 waves)
#define GB1     (N_NODES / 16)                       // 6250 gemm tiles
#define ROWBLKS ((N_NODES + 255) / 256)              // 391
#define XB_STRIDE 1440                               // padded bf16 row (2880B, 16B-aligned)
#define XB_TOTAL  ((size_t)N_NODES * XB_STRIDE)
#define NF4     (N_NODES * F_IN / 4)                 // 35,825,000 float4s (exact)
#define PBR     2048                                 // repack blocks (grid-stride)
#define PWB     12                                   // prep_w1 blocks (4 windows each)
#define QBLK    (N_EDGES / 4 / 256)                  // 3125 quad blocks (exact)
#define SCAN_BS 512
#define SCAN_NB ((N_NODES + SCAN_BS - 1) / SCAN_BS)  // 196

typedef __attribute__((ext_vector_type(8))) short short8v;
typedef __attribute__((ext_vector_type(4))) float float4v;

__device__ __forceinline__ unsigned short f2bf(float f) {
    unsigned u = __float_as_uint(f);
    u += 0x7fffu + ((u >> 16) & 1u);                 // RNE
    return (unsigned short)(u >> 16);
}

// ---------------- fat1: x->bf16 repack (first) ++ prep_w1 ++ count_deg -----
// Repack (R13-proven): read x FLAT as coalesced float4, scatter bf16 into xb
// stride 1440. Tail blocks: w1f fragment prep + CSR degree count (3.2M int
// atomics to 100k counters — R1/R7-proven ~30-50us, hides under repack BW).

__global__ __launch_bounds__(256) void fat1_kernel(const float* __restrict__ x,
                                                   short* __restrict__ xb,
                                                   const float* __restrict__ W1,
                                                   short* __restrict__ w1f,
                                                   const int* __restrict__ dst,
                                                   int* __restrict__ deg) {
    const int bid = blockIdx.x;
    if (bid < PBR) {
        // ---- repack path ----
        for (long i4 = (long)bid * 256 + threadIdx.x; i4 < NF4; i4 += (long)PBR * 256) {
            float4 v = ((const float4*)x)[i4];
            float fv[4] = {v.x, v.y, v.z, v.w};
            unsigned e0 = (unsigned)(i4 * 4);
#pragma unroll
            for (int j = 0; j < 4; ++j) {
                unsigned e = e0 + j;
                unsigned row = e / 1433u;             // magic-mul
                unsigned col = e - row * 1433u;
                xb[(size_t)row * XB_STRIDE + col] = (short)f2bf(fv[j]);
            }
        }
        for (int p = bid * 256 + threadIdx.x; p < N_NODES * 7; p += PBR * 256) {
            int row = p / 7;
            int col = 1433 + (p - row * 7);
            xb[(size_t)row * XB_STRIDE + col] = 0;
        }
        return;
    }
    if (bid < PBR + PWB) {
        // ---- prep_w1 path: 4 windows per block ----
        int w = (bid - PBR) * 4 + (threadIdx.x >> 6);
        int l = threadIdx.x & 63;
        int col = l & 15;
        int kb = w * 32 + ((l >> 4) & 3) * 8;
        short8v f;
#pragma unroll
        for (int i = 0; i < 8; ++i) {
            int k = kb + i;
            float v = (k < F_IN) ? W1[k * HID + col] : 0.f;
            f[i] = (short)f2bf(v);
        }
        *(short8v*)(w1f + ((size_t)w * 64 + l) * 8) = f;
        return;
    }
    // ---- count_deg path (int4 quads) ----
    int i = (bid - PBR - PWB) * 256 + threadIdx.x;
    int4 d4 = ((const int4*)dst)[i];                 // exact: 3125*256 = 800k
    atomicAdd(&deg[d4.x], 1);
    atomicAdd(&deg[d4.y], 1);
    atomicAdd(&deg[d4.z], 1);
    atomicAdd(&deg[d4.w], 1);
}

// ---------------- CSR scan chain (R2-verbatim, proven) ----------------

__global__ void scan_block_kernel(const int* __restrict__ deg, int* __restrict__ off,
                                  int* __restrict__ bsum) {
    __shared__ int s[SCAN_BS];
    int t = threadIdx.x;
    int g = blockIdx.x * SCAN_BS + t;
    int v = (g < N_NODES) ? deg[g] : 0;
    s[t] = v;
    __syncthreads();
    for (int d = 1; d < SCAN_BS; d <<= 1) {
        int add = (t >= d) ? s[t - d] : 0;
        __syncthreads();
        s[t] += add;
        __syncthreads();
    }
    if (g < N_NODES) off[g] = s[t] - v;
    if (t == SCAN_BS - 1) bsum[blockIdx.x] = s[t];
}

__global__ void scan_sums_kernel(int* __restrict__ bsum) {
    __shared__ int s[256];
    int t = threadIdx.x;
    int v = (t < SCAN_NB) ? bsum[t] : 0;
    s[t] = v;
    __syncthreads();
    for (int d = 1; d < 256; d <<= 1) {
        int add = (t >= d) ? s[t - d] : 0;
        __syncthreads();
        s[t] += add;
        __syncthreads();
    }
    if (t < SCAN_NB) bsum[t] = s[t] - v;
}

__global__ void add_base_kernel(int* __restrict__ off, const int* __restrict__ bsum,
                                int* __restrict__ cur) {
    int t = threadIdx.x;
    int b = blockIdx.x;
    int g = b * SCAN_BS + t;
    if (g < N_NODES) {
        int o = off[g] + bsum[b];
        off[g] = o;
        cur[g] = o;
    }
}

// ---------------- fat2: gemm1 tiles (first) ++ fill_csr (tail) ----------------
// gemm (R13/R18-verbatim): aligned dwordx4 A-frags from xb, all 12 windows
// straight-line into registers (VGPR~128; launch_bounds essential per R10).
// fill_csr (R7-proven): returning atomics + 12.8MB scatter; partial lines
// merge in memory-side L3. Tail-overlapped under the BW-bound gemm (R8 law).

__global__ __launch_bounds__(256) void fat2_kernel(const short* __restrict__ xb,
                                                   const short* __restrict__ w1f,
                                                   float* __restrict__ t1,
                                                   const int* __restrict__ src,
                                                   const int* __restrict__ dst,
                                                   int* __restrict__ cur,
                                                   int* __restrict__ csr) {
    const int bid = blockIdx.x;
    if (bid >= GB1) {
        // ---- fill_csr path ----
        int i = (bid - GB1) * 256 + threadIdx.x;
        int4 s4 = ((const int4*)src)[i];
        int4 d4 = ((const int4*)dst)[i];
        csr[atomicAdd(&cur[d4.x], 1)] = s4.x;
        csr[atomicAdd(&cur[d4.y], 1)] = s4.y;
        csr[atomicAdd(&cur[d4.z], 1)] = s4.z;
        csr[atomicAdd(&cur[d4.w], 1)] = s4.w;
        return;
    }
    // ---- gemm1 path ----
    __shared__ float red[4][256];
    const int tid = threadIdx.x;
    const int s = tid >> 6;                // wave / K-slice
    const int l = tid & 63;                // lane
    const int R0 = bid * 16;
    const int g = l >> 4;                  // k-group
    const int c = l & 15;                  // A row / B col
    const int row = R0 + c;
    const size_t base = (size_t)row * XB_STRIDE + g * 8;
    const short* __restrict__ wfp = w1f + ((size_t)(s * NWIN) * 64 + l) * 8;

    short8v bf[NWIN];
#pragma unroll
    for (int wl = 0; wl < NWIN; ++wl)
        bf[wl] = *(const short8v*)(wfp + (size_t)wl * 512);

    short8v af[NWIN];
#pragma unroll
    for (int wl = 0; wl < NWIN; ++wl) {
        size_t off = base + (size_t)(s * NWIN + wl) * 32;
        if (off > XB_TOTAL - 8) off = XB_TOTAL - 8;   // last-row k>=1440 tail
        af[wl] = *(const short8v*)(xb + off);
    }

    float4v acc = {0.f, 0.f, 0.f, 0.f};
#pragma unroll
    for (int wl = 0; wl < NWIN; ++wl)
        acc = __builtin_amdgcn_mfma_f32_16x16x32_bf16(af[wl], bf[wl], acc, 0, 0, 0);

    // cross-wave K reduction (D map: col=l&15, row=4*(l>>4)+j — verified R6+)
#pragma unroll
    for (int j = 0; j < 4; ++j) red[s][l * 4 + j] = acc[j];
    __syncthreads();
    {
        int r = tid >> 4, cc = tid & 15;
        int idx = ((r >> 2) * 16 + cc) * 4 + (r & 3);
        float vv = red[0][idx] + red[1][idx] + red[2][idx] + red[3][idx];
        t1[(long)(R0 + r) * HID + cc] = vv;
    }
}

// h = relu(gather-sum(t1) + t1 + b1); 4 lanes/node, float4 CSR gathers (R7)
__global__ void agg1_kernel(const float* __restrict__ t1, const int* __restrict__ off,
                            const int* __restrict__ deg, const int* __restrict__ csr,
                            const float* __restrict__ b1, float* __restrict__ h) {
    int tid = blockIdx.x * blockDim.x + threadIdx.x;
    if (tid >= N_NODES * 4) return;
    int node = tid >> 2;
    int q = tid & 3;
    int o = off[node];
    int d = deg[node];
    float4 a = *(const float4*)(t1 + ((size_t)node * 16 + q * 4));
    float4 b = *(const float4*)(b1 + q * 4);
    a.x += b.x; a.y += b.y; a.z += b.z; a.w += b.w;
    for (int e = 0; e < d; ++e) {
        int s = csr[o + e];
        float4 v = *(const float4*)(t1 + ((size_t)s * 16 + q * 4));
        a.x += v.x; a.y += v.y; a.z += v.z; a.w += v.w;
    }
    float4 r = {fmaxf(a.x, 0.f), fmaxf(a.y, 0.f), fmaxf(a.z, 0.f), fmaxf(a.w, 0.f)};
    *(float4*)(h + ((size_t)node * 16 + q * 4)) = r;
}

// ---------------- layer 2 (t2 padded to stride 8) ----------------

__global__ void gemm2_kernel(const float* __restrict__ h, const float* __restrict__ W2,
                             float* __restrict__ t2p) {
    int node = blockIdx.x * blockDim.x + threadIdx.x;
    if (node >= N_NODES) return;
    const float4* hr = (const float4*)(h + (size_t)node * HID);
    float hv[HID];
    ((float4*)hv)[0] = hr[0];
    ((float4*)hv)[1] = hr[1];
    ((float4*)hv)[2] = hr[2];
    ((float4*)hv)[3] = hr[3];
    float o8[8];
#pragma unroll
    for (int cNum = 0; cNum < N_CLS; ++cNum) {
        float a = 0.f;
#pragma unroll
        for (int j = 0; j < HID; ++j) a = fmaf(hv[j], W2[j * N_CLS + cNum], a);
        o8[cNum] = a;
    }
    o8[7] = 0.f;
    float4* op = (float4*)(t2p + (size_t)node * 8);
    op[0] = ((float4*)o8)[0];
    op[1] = ((float4*)o8)[1];
}

// out = gather-sum(t2) + t2 + b2; 2 lanes/node, float4 CSR gathers (R7)
__global__ void agg2_kernel(const float* __restrict__ t2p, const int* __restrict__ off,
                            const int* __restrict__ deg, const int* __restrict__ csr,
                            const float* __restrict__ b2, float* __restrict__ out) {
    int tid = blockIdx.x * blockDim.x + threadIdx.x;
    if (tid >= N_NODES * 2) return;
    int node = tid >> 1;
    int q = tid & 1;
    int o = off[node];
    int d = deg[node];
    float4 a = *(const float4*)(t2p + ((size_t)node * 8 + q * 4));
    if (q == 0) {
        a.x += b2[0]; a.y += b2[1]; a.z += b2[2]; a.w += b2[3];
    } else {
        a.x += b2[4]; a.y += b2[5]; a.z += b2[6];
    }
    for (int e = 0; e < d; ++e) {
        int s = csr[o + e];
        float4 v = *(const float4*)(t2p + ((size_t)s * 8 + q * 4));
        a.x += v.x; a.y += v.y; a.z += v.z; a.w += v.w;
    }
    float* op = out + (size_t)node * 7 + q * 4;
    op[0] = a.x; op[1] = a.y; op[2] = a.z;
    if (q == 0) op[3] = a.w;
}

// ---------------- launch ----------------

extern "C" void kernel_launch(void* const* d_in, const int* in_sizes, int n_in,
                              void* d_out, int out_size, void* d_ws, size_t ws_size,
                              hipStream_t stream) {
    const float* x  = (const float*)d_in[0];
    const int*   ei = (const int*)d_in[1];
    const float* W1 = (const float*)d_in[2];
    const float* b1 = (const float*)d_in[3];
    const float* W2 = (const float*)d_in[4];
    const float* b2 = (const float*)d_in[5];
    const int* src = ei;
    const int* dst = ei + N_EDGES;
    float* out = (float*)d_out;

    char* w = (char*)d_ws;
    float* t1  = (float*)w;  w += (size_t)N_NODES * HID * sizeof(float);
    float* h   = (float*)w;  w += (size_t)N_NODES * HID * sizeof(float);
    float* t2p = (float*)w;  w += (size_t)N_NODES * 8 * sizeof(float);
    int* deg   = (int*)w;    w += (size_t)N_NODES * sizeof(int);
    int* off   = (int*)w;    w += (size_t)N_NODES * sizeof(int);
    int* cur   = (int*)w;    w += (size_t)N_NODES * sizeof(int);
    int* bsum  = (int*)w;    w += 256 * sizeof(int);
    int* csr   = (int*)w;    w += (size_t)N_EDGES * sizeof(int);
    short* w1f = (short*)w;  w += (size_t)NWINT * 64 * 8 * sizeof(short);
    short* xb  = (short*)w;  w += XB_TOTAL * sizeof(short) + 256;  // +slack

    hipMemsetAsync(deg, 0, (size_t)N_NODES * sizeof(int), stream);

    // repack (first) ++ prep_w1 ++ count_deg (tail)
    fat1_kernel<<<PBR + PWB + QBLK, 256, 0, stream>>>(x, xb, W1, w1f, dst, deg);

    scan_block_kernel<<<SCAN_NB, SCAN_BS, 0, stream>>>(deg, off, bsum);
    scan_sums_kernel<<<1, 256, 0, stream>>>(bsum);
    add_base_kernel<<<SCAN_NB, SCAN_BS, 0, stream>>>(off, bsum, cur);

    // gemm1 (first) ++ fill_csr (tail)
    fat2_kernel<<<GB1 + QBLK, 256, 0, stream>>>(xb, w1f, t1, src, dst, cur, csr);

    agg1_kernel<<<(N_NODES * 4 + 255) / 256, 256, 0, stream>>>(t1, off, deg, csr, b1, h);
    gemm2_kernel<<<ROWBLKS, 256, 0, stream>>>(h, W2, t2p);
    agg2_kernel<<<(N_NODES * 2 + 255) / 256, 256, 0, stream>>>(t2p, off, deg, csr, b2, out);
}